// Round 11
// baseline (103.863 us; speedup 1.0000x reference)
//
#include <hip/hip_runtime.h>
#include <stdint.h>

// MinimumErrorRateLoss: unit-cost Levenshtein via Myers/Hyyrö bit-parallel DP.
// R11 = R10 (90.0 µs: u32 8-way systolic word split, R=4 steps/phase,
// idempotent padding, unroll 2) + three micro-levers:
//  1. hyp_len precomputed per sample in the prologue -> hot loop's score
//     guard is ONE cmp+cndmask on (base+I < hlen); the done-flag, pvalid,
//     EOS check, and current-phase token unpack/register are deleted.
//  2. pair-packed u32 transpose staging (16 ds_write_b32 vs 32 ds_write_b16
//     per thread).
//  3. loss epilogue fused into one 1024-thread kernel (R8's mer_tail,
//     verified absmax 0) -> one fewer dispatch.
//
// Layout (fixed problem size):
//   log_probs: (128, 64) f32      -> lp[b*64+s]
//   ref:       (256, 128) i32     -> ref[j*128+b]   (shared across samples)
//   hyp:       (256, 128, 64) i32 -> hyp[t*8192 + b*64 + s]
//   out:       scalar f32
// EOS = 0, INCLUDE_EOS -> len = first-EOS-idx + 1, else T.

#define BATCH   128
#define SAMPLES 64
#define RLEN    256
#define HLEN    256
#define NSEQ    (BATCH*SAMPLES)
#define NTOK    1000
#define PADTOK  1000       // pm has 1001 rows; row 1000 stays all-zero
#define SPB     32         // samples per block
#define PMSTR   9          // pm row stride in u32 (8 data + 1 pad)
#define HEADPAD 28         // pad tokens before t=0 (covers base >= -28)
#define HTROW   324        // 28 + 256 + 40 u16 = 648 B/row (8-B aligned)
#define RSTEP   4          // DP steps per systolic phase
#define NPH     72         // 256/4 + 8 - 1 = 71, +1 (even, for unroll 2)

typedef unsigned long long u64;
typedef unsigned int       u32;

// DPP row_shr:1 -> lane i reads lane i-1 within rows of 16; row-lane-0 gets 0.
__device__ __forceinline__ int row_shr1(int x) {
    return __builtin_amdgcn_mov_dpp(x, 0x111, 0xf, 0xf, true);
}

__global__ __launch_bounds__(256) void mer_edit(const int* __restrict__ ref,
                                                const int* __restrict__ hyp,
                                                int* __restrict__ scores,
                                                int* __restrict__ reflen)
{
    const int blk  = blockIdx.x;      // 0..255
    const int b    = blk >> 1;        // batch element
    const int half = blk & 1;         // sample half (0: s 0..31, 1: s 32..63)
    const int tid  = threadIdx.x;     // 0..255
    const int w    = tid & 7;         // u32 word 0..7
    const int sl   = tid >> 3;        // local sample 0..31

    __shared__ __align__(16) u32 pm[9012];                   // 1001*9=9009 (+pad)
    __shared__ __align__(8)  unsigned short ht[SPB * HTROW]; // 20736 B
    __shared__ int m_sh;

    if (tid == 0) m_sh = RLEN;

    // ---- zero PM (9012 u32 = 2253 int4) ----
    for (int i = tid; i < 2253; i += 256)
        ((int4*)pm)[i] = int4{0, 0, 0, 0};

    // ---- fill ht pad regions with PADTOK ----
    // row = 162 u32: head [0,14), data [14,142), tail [142,162) -> 34 pads
    {
        const int r = tid >> 3, c = tid & 7;       // row 0..31, chunk 0..7
        u32* rowp = (u32*)ht + r * (HTROW / 2);
#pragma unroll
        for (int j0 = 0; j0 < 5; ++j0) {
            int j = c * 5 + j0;                    // 0..39; need 0..33
            if (j < 34) {
                int off = (j < 14) ? j : (142 + (j - 14));
                rowp[off] = 0x03E803E8u;           // PADTOK | PADTOK<<16
            }
        }
    }

    // ---- stage hyp slab TRANSPOSED, pair-packed:
    //      ht[s][HEADPAD + 2p..2p+1] <- one u32 write (little-endian: lo=2p)
#pragma unroll
    for (int it = 0; it < 4; it++) {
        int idx = it * 256 + tid;     // 0..1023
        int p   = idx >> 3;           // t-pair 0..127
        int s4  = (idx & 7) * 4;      // 0,4,..,28
        const int* gp = hyp + b * SAMPLES + half * SPB + s4;
        int4 v0 = *(const int4*)(gp + (2 * p)     * NSEQ);
        int4 v1 = *(const int4*)(gp + (2 * p + 1) * NSEQ);
        u32* col = (u32*)ht + (HEADPAD + 2 * p) / 2;
        col[(s4 + 0) * (HTROW / 2)] = (u32)(unsigned short)v0.x | ((u32)(unsigned short)v1.x << 16);
        col[(s4 + 1) * (HTROW / 2)] = (u32)(unsigned short)v0.y | ((u32)(unsigned short)v1.y << 16);
        col[(s4 + 2) * (HTROW / 2)] = (u32)(unsigned short)v0.z | ((u32)(unsigned short)v1.z << 16);
        col[(s4 + 3) * (HTROW / 2)] = (u32)(unsigned short)v0.w | ((u32)(unsigned short)v1.w << 16);
    }

    // ---- ref column: one token per thread (j = tid) ----
    const int rt = ref[tid * BATCH + b];
    __syncthreads();                  // m_sh + pm zero done
    if (rt == 0) atomicMin(&m_sh, tid);
    __syncthreads();
    const int m = (m_sh < RLEN) ? (m_sh + 1) : RLEN;   // ref_len, 1..256
    if (tid < m)
        atomicOr(&pm[rt * PMSTR + (tid >> 5)], 1u << (tid & 31));
    __syncthreads();                  // pm + ht ready; no more barriers

    // ---- per-sample hyp_len: thread (sl,w) scans t in [32w, 32w+32) ----
    u32 hlen;
    {
        const u32* rowp32 = (const u32*)(ht + sl * HTROW + HEADPAD);
        int e = 256;
#pragma unroll
        for (int j = 0; j < 16; j++) {
            u32 v  = rowp32[w * 16 + j];
            int t0 = w * 32 + 2 * j;
            if ((v & 0xFFFFu) == 0) e = min(e, t0);
            if ((v >> 16)     == 0) e = min(e, t0 + 1);
        }
        e = min(e, __shfl_xor(e, 1));   // reduce across the 8 word-lanes
        e = min(e, __shfl_xor(e, 2));   // (contiguous: tid = sl*8 + w)
        e = min(e, __shfl_xor(e, 4));
        hlen = (e < 256) ? (u32)(e + 1) : 256u;
    }

    // ---- systolic-in-wave Myers, u32 words, 4 steps/phase ----
    const int  sw   = (m - 1) >> 5, sb = (m - 1) & 31;  // score bit location
    const bool isW0 = (w == 0);
    const bool isSW = (w == sw);
    const u32* pmw  = pm + w;
    const unsigned short* htrow = ht + sl * HTROW + HEADPAD;

    u32  VP = ~0u, VN = 0u;
    int  score = m;
    int  base  = -(w << 2);           // this phase's first DP step (mult of 4)

    // prime: Eq for phase 0's tokens; tkB = phase 1's packed tokens
    uint2 tkB = *(const uint2*)(htrow + base + 4);
    u32 eqA0, eqA1, eqA2, eqA3;
    {
        uint2 tkA = *(const uint2*)(htrow + base);   // pads: always in-bounds
        u32 p0 = tkA.x & 0xFFFFu, p1 = tkA.x >> 16;
        u32 p2 = tkA.y & 0xFFFFu, p3 = tkA.y >> 16;
        eqA0 = pmw[p0 * PMSTR]; eqA1 = pmw[p1 * PMSTR];
        eqA2 = pmw[p2 * PMSTR]; eqA3 = pmw[p3 * PMSTR];
    }

    int out_pkd = 0;   // 12-bit carry packet from my previous phase

#define STEP(EQ, I) do {                                                  \
        u32 cin  = ((u32)inp >> (I)) & 1u;                                \
        u32 hpin = ((u32)inp >> (8 + (I))) & 1u;                          \
        u32 hnin = ((u32)inp >> (16 + (I))) & 1u;                         \
        u32 x  = (EQ) & VP;                                               \
        u64 S  = (u64)x + VP + cin;                                       \
        u32 s2 = (u32)S;                                                  \
        u32 D0 = (s2 ^ VP) | (EQ) | VN;                                   \
        u32 HP = VN | ~(D0 | VP);                                         \
        u32 HN = VP & D0;                                                 \
        nout |= ((u32)(S >> 32) << (I)) | ((HP >> 31) << (8 + (I)))       \
                | ((HN >> 31) << (16 + (I)));                             \
        int delta = (int)((HP >> sb) & 1u) - (int)((HN >> sb) & 1u);      \
        u32 HPs = (HP << 1) | hpin;                                       \
        u32 HNs = (HN << 1) | hnin;                                       \
        VP = HNs | ~(D0 | HPs);                                           \
        VN = HPs & D0;                                                    \
        score += ((u32)(base + (I)) < hlen) ? delta : 0;                  \
    } while (0)

#pragma unroll 2
    for (int P = 0; P < NPH; ++P) {
        // token prefetch for phase P+2 (pads guarantee in-bounds, no clamps)
        uint2 tkC = *(const uint2*)(htrow + base + 8);

        // Eq loads for phase P+1 tokens (tkB, loaded last phase)
        u32 n0 = tkB.x & 0xFFFFu, n1 = tkB.x >> 16;
        u32 n2 = tkB.y & 0xFFFFu, n3 = tkB.y >> 16;
        u32 eqB0 = pmw[n0 * PMSTR], eqB1 = pmw[n1 * PMSTR];
        u32 eqB2 = pmw[n2 * PMSTR], eqB3 = pmw[n3 * PMSTR];

        // carry packet from word w-1 (its previous phase), one DPP
        int inp = row_shr1(out_pkd);
        if (isW0) inp = 0x0F00;       // cin=0, hpin=1 (D[0][j]=j), hnin=0 x4

        u32 nout = 0;
        STEP(eqA0, 0);
        STEP(eqA1, 1);
        STEP(eqA2, 2);
        STEP(eqA3, 3);
        out_pkd = (int)nout;

        // rotate pipeline
        tkB = tkC;
        eqA0 = eqB0; eqA1 = eqB1; eqA2 = eqB2; eqA3 = eqB3;
        base += RSTEP;
    }
#undef STEP

    if (isSW) scores[b * SAMPLES + half * SPB + sl] = score;
    if (half == 0 && tid == 0) reflen[b] = m;
}

// Single block, 1024 threads = 16 waves; wave wv handles batches wv*8..wv*8+7.
//   per-batch: sum_s (er - mean_er)*softmax = dot(er,p)/sumexp - mean_er
__global__ __launch_bounds__(1024) void mer_tail(const float* __restrict__ lp,
                                                 const int* __restrict__ scores,
                                                 const int* __restrict__ reflen,
                                                 float* __restrict__ out)
{
    const int tid = threadIdx.x;
    const int s   = tid & 63;
    const int wv  = tid >> 6;         // 0..15
    __shared__ double red[16];

    double acc = 0.0;
#pragma unroll
    for (int k = 0; k < 8; k++) {
        const int b  = wv * 8 + k;
        double er = (double)scores[b * SAMPLES + s] / (double)reflen[b];
        double x  = (double)lp[b * SAMPLES + s];
        double mx = x;
#pragma unroll
        for (int off = 32; off > 0; off >>= 1)
            mx = fmax(mx, __shfl_xor(mx, off));
        double e = exp(x - mx);
        double se = e, see = er * e, ser = er;
#pragma unroll
        for (int off = 32; off > 0; off >>= 1) {
            se  += __shfl_xor(se,  off);
            see += __shfl_xor(see, off);
            ser += __shfl_xor(ser, off);
        }
        if (s == 0) acc += see / se - ser * (1.0 / SAMPLES);
    }
    if (s == 0) red[wv] = acc;
    __syncthreads();
    if (tid == 0) {
        double v = 0.0;
#pragma unroll
        for (int i = 0; i < 16; i++) v += red[i];
        out[0] = (float)(v / (double)(BATCH * SAMPLES));
    }
}

extern "C" void kernel_launch(void* const* d_in, const int* in_sizes, int n_in,
                              void* d_out, int out_size, void* d_ws, size_t ws_size,
                              hipStream_t stream)
{
    const float* lp  = (const float*)d_in[0];
    const int*   ref = (const int*)d_in[1];
    const int*   hyp = (const int*)d_in[2];

    int*   scores = (int*)d_ws;                  // 8192 i32
    int*   reflen = scores + NSEQ;               // 128 i32
    float* out    = (float*)d_out;

    mer_edit<<<2 * BATCH, 256, 0, stream>>>(ref, hyp, scores, reflen);
    mer_tail<<<1, 1024, 0, stream>>>(lp, scores, reflen, out);
}

// Round 12
// 89.170 us; speedup vs baseline: 1.1648x; 1.1648x over previous
//
#include <hip/hip_runtime.h>
#include <stdint.h>

// MinimumErrorRateLoss: unit-cost Levenshtein via Myers/Hyyrö bit-parallel DP.
// R12 = R11's mer_edit (hyp_len precompute + pair-packed staging) with the
// epilogue fusion REVERTED to R10's parallel two-kernel form.
// Cross-round evidence: every fused-mer_tail round (R8/R9/R11) = ~104-106 µs;
// every parallel-epilogue round (R7/R10) = ~90-93 µs. mer_tail serializes
// 8 f64 exp+div+shuffle chains per wave on ONE CU (~10 µs) vs ~2-4 µs for
// the 128-block mer_loss + tiny mer_final.
//
// Layout (fixed problem size):
//   log_probs: (128, 64) f32      -> lp[b*64+s]
//   ref:       (256, 128) i32     -> ref[j*128+b]   (shared across samples)
//   hyp:       (256, 128, 64) i32 -> hyp[t*8192 + b*64 + s]
//   out:       scalar f32
// EOS = 0, INCLUDE_EOS -> len = first-EOS-idx + 1, else T.

#define BATCH   128
#define SAMPLES 64
#define RLEN    256
#define HLEN    256
#define NSEQ    (BATCH*SAMPLES)
#define NTOK    1000
#define PADTOK  1000       // pm has 1001 rows; row 1000 stays all-zero
#define SPB     32         // samples per block
#define PMSTR   9          // pm row stride in u32 (8 data + 1 pad)
#define HEADPAD 28         // pad tokens before t=0 (covers base >= -28)
#define HTROW   324        // 28 + 256 + 40 u16 = 648 B/row (8-B aligned)
#define RSTEP   4          // DP steps per systolic phase
#define NPH     72         // 256/4 + 8 - 1 = 71, +1 (even, for unroll 2)

typedef unsigned long long u64;
typedef unsigned int       u32;

// DPP row_shr:1 -> lane i reads lane i-1 within rows of 16; row-lane-0 gets 0.
__device__ __forceinline__ int row_shr1(int x) {
    return __builtin_amdgcn_mov_dpp(x, 0x111, 0xf, 0xf, true);
}

__global__ __launch_bounds__(256) void mer_edit(const int* __restrict__ ref,
                                                const int* __restrict__ hyp,
                                                int* __restrict__ scores,
                                                int* __restrict__ reflen)
{
    const int blk  = blockIdx.x;      // 0..255
    const int b    = blk >> 1;        // batch element
    const int half = blk & 1;         // sample half (0: s 0..31, 1: s 32..63)
    const int tid  = threadIdx.x;     // 0..255
    const int w    = tid & 7;         // u32 word 0..7
    const int sl   = tid >> 3;        // local sample 0..31

    __shared__ __align__(16) u32 pm[9012];                   // 1001*9=9009 (+pad)
    __shared__ __align__(8)  unsigned short ht[SPB * HTROW]; // 20736 B
    __shared__ int m_sh;

    if (tid == 0) m_sh = RLEN;

    // ---- zero PM (9012 u32 = 2253 int4) ----
    for (int i = tid; i < 2253; i += 256)
        ((int4*)pm)[i] = int4{0, 0, 0, 0};

    // ---- fill ht pad regions with PADTOK ----
    // row = 162 u32: head [0,14), data [14,142), tail [142,162) -> 34 pads
    {
        const int r = tid >> 3, c = tid & 7;       // row 0..31, chunk 0..7
        u32* rowp = (u32*)ht + r * (HTROW / 2);
#pragma unroll
        for (int j0 = 0; j0 < 5; ++j0) {
            int j = c * 5 + j0;                    // 0..39; need 0..33
            if (j < 34) {
                int off = (j < 14) ? j : (142 + (j - 14));
                rowp[off] = 0x03E803E8u;           // PADTOK | PADTOK<<16
            }
        }
    }

    // ---- stage hyp slab TRANSPOSED, pair-packed:
    //      ht[s][HEADPAD + 2p..2p+1] <- one u32 write (little-endian: lo=2p)
#pragma unroll
    for (int it = 0; it < 4; it++) {
        int idx = it * 256 + tid;     // 0..1023
        int p   = idx >> 3;           // t-pair 0..127
        int s4  = (idx & 7) * 4;      // 0,4,..,28
        const int* gp = hyp + b * SAMPLES + half * SPB + s4;
        int4 v0 = *(const int4*)(gp + (2 * p)     * NSEQ);
        int4 v1 = *(const int4*)(gp + (2 * p + 1) * NSEQ);
        u32* col = (u32*)ht + (HEADPAD + 2 * p) / 2;
        col[(s4 + 0) * (HTROW / 2)] = (u32)(unsigned short)v0.x | ((u32)(unsigned short)v1.x << 16);
        col[(s4 + 1) * (HTROW / 2)] = (u32)(unsigned short)v0.y | ((u32)(unsigned short)v1.y << 16);
        col[(s4 + 2) * (HTROW / 2)] = (u32)(unsigned short)v0.z | ((u32)(unsigned short)v1.z << 16);
        col[(s4 + 3) * (HTROW / 2)] = (u32)(unsigned short)v0.w | ((u32)(unsigned short)v1.w << 16);
    }

    // ---- ref column: one token per thread (j = tid) ----
    const int rt = ref[tid * BATCH + b];
    __syncthreads();                  // m_sh + pm zero done
    if (rt == 0) atomicMin(&m_sh, tid);
    __syncthreads();
    const int m = (m_sh < RLEN) ? (m_sh + 1) : RLEN;   // ref_len, 1..256
    if (tid < m)
        atomicOr(&pm[rt * PMSTR + (tid >> 5)], 1u << (tid & 31));
    __syncthreads();                  // pm + ht ready; no more barriers

    // ---- per-sample hyp_len: thread (sl,w) scans t in [32w, 32w+32) ----
    u32 hlen;
    {
        const u32* rowp32 = (const u32*)(ht + sl * HTROW + HEADPAD);
        int e = 256;
#pragma unroll
        for (int j = 0; j < 16; j++) {
            u32 v  = rowp32[w * 16 + j];
            int t0 = w * 32 + 2 * j;
            if ((v & 0xFFFFu) == 0) e = min(e, t0);
            if ((v >> 16)     == 0) e = min(e, t0 + 1);
        }
        e = min(e, __shfl_xor(e, 1));   // reduce across the 8 word-lanes
        e = min(e, __shfl_xor(e, 2));   // (contiguous: tid = sl*8 + w)
        e = min(e, __shfl_xor(e, 4));
        hlen = (e < 256) ? (u32)(e + 1) : 256u;
    }

    // ---- systolic-in-wave Myers, u32 words, 4 steps/phase ----
    const int  sw   = (m - 1) >> 5, sb = (m - 1) & 31;  // score bit location
    const bool isW0 = (w == 0);
    const bool isSW = (w == sw);
    const u32* pmw  = pm + w;
    const unsigned short* htrow = ht + sl * HTROW + HEADPAD;

    u32  VP = ~0u, VN = 0u;
    int  score = m;
    int  base  = -(w << 2);           // this phase's first DP step (mult of 4)

    // prime: Eq for phase 0's tokens; tkB = phase 1's packed tokens
    uint2 tkB = *(const uint2*)(htrow + base + 4);
    u32 eqA0, eqA1, eqA2, eqA3;
    {
        uint2 tkA = *(const uint2*)(htrow + base);   // pads: always in-bounds
        u32 p0 = tkA.x & 0xFFFFu, p1 = tkA.x >> 16;
        u32 p2 = tkA.y & 0xFFFFu, p3 = tkA.y >> 16;
        eqA0 = pmw[p0 * PMSTR]; eqA1 = pmw[p1 * PMSTR];
        eqA2 = pmw[p2 * PMSTR]; eqA3 = pmw[p3 * PMSTR];
    }

    int out_pkd = 0;   // 12-bit carry packet from my previous phase

#define STEP(EQ, I) do {                                                  \
        u32 cin  = ((u32)inp >> (I)) & 1u;                                \
        u32 hpin = ((u32)inp >> (8 + (I))) & 1u;                          \
        u32 hnin = ((u32)inp >> (16 + (I))) & 1u;                         \
        u32 x  = (EQ) & VP;                                               \
        u64 S  = (u64)x + VP + cin;                                       \
        u32 s2 = (u32)S;                                                  \
        u32 D0 = (s2 ^ VP) | (EQ) | VN;                                   \
        u32 HP = VN | ~(D0 | VP);                                         \
        u32 HN = VP & D0;                                                 \
        nout |= ((u32)(S >> 32) << (I)) | ((HP >> 31) << (8 + (I)))       \
                | ((HN >> 31) << (16 + (I)));                             \
        int delta = (int)((HP >> sb) & 1u) - (int)((HN >> sb) & 1u);      \
        u32 HPs = (HP << 1) | hpin;                                       \
        u32 HNs = (HN << 1) | hnin;                                       \
        VP = HNs | ~(D0 | HPs);                                           \
        VN = HPs & D0;                                                    \
        score += ((u32)(base + (I)) < hlen) ? delta : 0;                  \
    } while (0)

#pragma unroll 2
    for (int P = 0; P < NPH; ++P) {
        // token prefetch for phase P+2 (pads guarantee in-bounds, no clamps)
        uint2 tkC = *(const uint2*)(htrow + base + 8);

        // Eq loads for phase P+1 tokens (tkB, loaded last phase)
        u32 n0 = tkB.x & 0xFFFFu, n1 = tkB.x >> 16;
        u32 n2 = tkB.y & 0xFFFFu, n3 = tkB.y >> 16;
        u32 eqB0 = pmw[n0 * PMSTR], eqB1 = pmw[n1 * PMSTR];
        u32 eqB2 = pmw[n2 * PMSTR], eqB3 = pmw[n3 * PMSTR];

        // carry packet from word w-1 (its previous phase), one DPP
        int inp = row_shr1(out_pkd);
        if (isW0) inp = 0x0F00;       // cin=0, hpin=1 (D[0][j]=j), hnin=0 x4

        u32 nout = 0;
        STEP(eqA0, 0);
        STEP(eqA1, 1);
        STEP(eqA2, 2);
        STEP(eqA3, 3);
        out_pkd = (int)nout;

        // rotate pipeline
        tkB = tkC;
        eqA0 = eqB0; eqA1 = eqB1; eqA2 = eqB2; eqA3 = eqB3;
        base += RSTEP;
    }
#undef STEP

    if (isSW) scores[b * SAMPLES + half * SPB + sl] = score;
    if (half == 0 && tid == 0) reflen[b] = m;
}

// Grid 128 x 64 threads: per-batch f64 loss partial.
//   sum_s (er - mean_er)*softmax = dot(er,p)/sumexp - mean_er  (sum p = 1)
__global__ __launch_bounds__(64) void mer_loss(const float* __restrict__ lp,
                                               const int* __restrict__ scores,
                                               const int* __restrict__ reflen,
                                               double* __restrict__ partial)
{
    const int b = blockIdx.x, s = threadIdx.x;
    double er = (double)scores[b * SAMPLES + s] / (double)reflen[b];
    double x  = (double)lp[b * SAMPLES + s];
    double mx = x;
#pragma unroll
    for (int off = 32; off > 0; off >>= 1)
        mx = fmax(mx, __shfl_xor(mx, off));
    double e = exp(x - mx);
    double se = e, see = er * e, ser = er;
#pragma unroll
    for (int off = 32; off > 0; off >>= 1) {
        se  += __shfl_xor(se,  off);
        see += __shfl_xor(see, off);
        ser += __shfl_xor(ser, off);
    }
    if (s == 0) partial[b] = see / se - ser * (1.0 / SAMPLES);
}

// 1 block, 64 threads: sum 128 per-batch partials, scale, write scalar.
__global__ __launch_bounds__(64) void mer_final(const double* __restrict__ partial,
                                                float* __restrict__ out)
{
    const int tid = threadIdx.x;
    double v = partial[tid] + partial[tid + 64];
#pragma unroll
    for (int off = 32; off > 0; off >>= 1)
        v += __shfl_xor(v, off);
    if (tid == 0) out[0] = (float)(v / (double)(BATCH * SAMPLES));
}

extern "C" void kernel_launch(void* const* d_in, const int* in_sizes, int n_in,
                              void* d_out, int out_size, void* d_ws, size_t ws_size,
                              hipStream_t stream)
{
    const float* lp  = (const float*)d_in[0];
    const int*   ref = (const int*)d_in[1];
    const int*   hyp = (const int*)d_in[2];

    double* partial = (double*)d_ws;                   // 128 f64
    int*    scores  = (int*)(partial + BATCH);         // 8192 i32
    int*    reflen  = scores + NSEQ;                   // 128 i32
    float*  out     = (float*)d_out;

    mer_edit<<<2 * BATCH, 256, 0, stream>>>(ref, hyp, scores, reflen);
    mer_loss<<<BATCH, 64, 0, stream>>>(lp, scores, reflen, partial);
    mer_final<<<1, 64, 0, stream>>>(partial, out);
}

// Round 13
// 87.391 us; speedup vs baseline: 1.1885x; 1.0204x over previous
//
#include <hip/hip_runtime.h>
#include <stdint.h>

// MinimumErrorRateLoss: unit-cost Levenshtein via Myers/Hyyrö bit-parallel DP.
// R13 = R12 (89.2 µs) with mer_loss DELETED: each mer_edit block (one
// 32-sample half-batch) computes its f64 partial sums (se, see, ser) in a
// short first-wave tail — exp without max-subtraction (f64, |x|<6: exact
// same math as softmax, ~1e-16 rel) — written to distinct slots (no
// atomics). mer_final combines halves and reduces. One dispatch fewer;
// mer_edit hot loop is byte-identical to R12's.
//
// Layout (fixed problem size):
//   log_probs: (128, 64) f32      -> lp[b*64+s]
//   ref:       (256, 128) i32     -> ref[j*128+b]   (shared across samples)
//   hyp:       (256, 128, 64) i32 -> hyp[t*8192 + b*64 + s]
//   out:       scalar f32
// EOS = 0, INCLUDE_EOS -> len = first-EOS-idx + 1, else T.

#define BATCH   128
#define SAMPLES 64
#define RLEN    256
#define HLEN    256
#define NSEQ    (BATCH*SAMPLES)
#define NTOK    1000
#define PADTOK  1000       // pm has 1001 rows; row 1000 stays all-zero
#define SPB     32         // samples per block
#define PMSTR   9          // pm row stride in u32 (8 data + 1 pad)
#define HEADPAD 28         // pad tokens before t=0 (covers base >= -28)
#define HTROW   324        // 28 + 256 + 40 u16 = 648 B/row (8-B aligned)
#define RSTEP   4          // DP steps per systolic phase
#define NPH     72         // 256/4 + 8 - 1 = 71, +1 (even, for unroll 2)

typedef unsigned long long u64;
typedef unsigned int       u32;

// DPP row_shr:1 -> lane i reads lane i-1 within rows of 16; row-lane-0 gets 0.
__device__ __forceinline__ int row_shr1(int x) {
    return __builtin_amdgcn_mov_dpp(x, 0x111, 0xf, 0xf, true);
}

__global__ __launch_bounds__(256) void mer_edit(const float* __restrict__ lp,
                                                const int* __restrict__ ref,
                                                const int* __restrict__ hyp,
                                                double* __restrict__ part)
{
    const int blk  = blockIdx.x;      // 0..255
    const int b    = blk >> 1;        // batch element
    const int half = blk & 1;         // sample half (0: s 0..31, 1: s 32..63)
    const int tid  = threadIdx.x;     // 0..255
    const int w    = tid & 7;         // u32 word 0..7
    const int sl   = tid >> 3;        // local sample 0..31

    __shared__ __align__(16) u32 pm[9012];                   // 1001*9=9009 (+pad)
    __shared__ __align__(8)  unsigned short ht[SPB * HTROW]; // 20736 B
    __shared__ int sc_sh[SPB];
    __shared__ int m_sh;

    if (tid == 0) m_sh = RLEN;

    // ---- zero PM (9012 u32 = 2253 int4) ----
    for (int i = tid; i < 2253; i += 256)
        ((int4*)pm)[i] = int4{0, 0, 0, 0};

    // ---- fill ht pad regions with PADTOK ----
    // row = 162 u32: head [0,14), data [14,142), tail [142,162) -> 34 pads
    {
        const int r = tid >> 3, c = tid & 7;       // row 0..31, chunk 0..7
        u32* rowp = (u32*)ht + r * (HTROW / 2);
#pragma unroll
        for (int j0 = 0; j0 < 5; ++j0) {
            int j = c * 5 + j0;                    // 0..39; need 0..33
            if (j < 34) {
                int off = (j < 14) ? j : (142 + (j - 14));
                rowp[off] = 0x03E803E8u;           // PADTOK | PADTOK<<16
            }
        }
    }

    // ---- stage hyp slab TRANSPOSED, pair-packed:
    //      ht[s][HEADPAD + 2p..2p+1] <- one u32 write (little-endian: lo=2p)
#pragma unroll
    for (int it = 0; it < 4; it++) {
        int idx = it * 256 + tid;     // 0..1023
        int p   = idx >> 3;           // t-pair 0..127
        int s4  = (idx & 7) * 4;      // 0,4,..,28
        const int* gp = hyp + b * SAMPLES + half * SPB + s4;
        int4 v0 = *(const int4*)(gp + (2 * p)     * NSEQ);
        int4 v1 = *(const int4*)(gp + (2 * p + 1) * NSEQ);
        u32* col = (u32*)ht + (HEADPAD + 2 * p) / 2;
        col[(s4 + 0) * (HTROW / 2)] = (u32)(unsigned short)v0.x | ((u32)(unsigned short)v1.x << 16);
        col[(s4 + 1) * (HTROW / 2)] = (u32)(unsigned short)v0.y | ((u32)(unsigned short)v1.y << 16);
        col[(s4 + 2) * (HTROW / 2)] = (u32)(unsigned short)v0.z | ((u32)(unsigned short)v1.z << 16);
        col[(s4 + 3) * (HTROW / 2)] = (u32)(unsigned short)v0.w | ((u32)(unsigned short)v1.w << 16);
    }

    // ---- ref column: one token per thread (j = tid) ----
    const int rt = ref[tid * BATCH + b];
    __syncthreads();                  // m_sh + pm zero done
    if (rt == 0) atomicMin(&m_sh, tid);
    __syncthreads();
    const int m = (m_sh < RLEN) ? (m_sh + 1) : RLEN;   // ref_len, 1..256
    if (tid < m)
        atomicOr(&pm[rt * PMSTR + (tid >> 5)], 1u << (tid & 31));
    __syncthreads();                  // pm + ht ready

    // ---- per-sample hyp_len: thread (sl,w) scans t in [32w, 32w+32) ----
    u32 hlen;
    {
        const u32* rowp32 = (const u32*)(ht + sl * HTROW + HEADPAD);
        int e = 256;
#pragma unroll
        for (int j = 0; j < 16; j++) {
            u32 v  = rowp32[w * 16 + j];
            int t0 = w * 32 + 2 * j;
            if ((v & 0xFFFFu) == 0) e = min(e, t0);
            if ((v >> 16)     == 0) e = min(e, t0 + 1);
        }
        e = min(e, __shfl_xor(e, 1));   // reduce across the 8 word-lanes
        e = min(e, __shfl_xor(e, 2));   // (contiguous: tid = sl*8 + w)
        e = min(e, __shfl_xor(e, 4));
        hlen = (e < 256) ? (u32)(e + 1) : 256u;
    }

    // ---- systolic-in-wave Myers, u32 words, 4 steps/phase ----
    const int  sw   = (m - 1) >> 5, sb = (m - 1) & 31;  // score bit location
    const bool isW0 = (w == 0);
    const bool isSW = (w == sw);
    const u32* pmw  = pm + w;
    const unsigned short* htrow = ht + sl * HTROW + HEADPAD;

    u32  VP = ~0u, VN = 0u;
    int  score = m;
    int  base  = -(w << 2);           // this phase's first DP step (mult of 4)

    // prime: Eq for phase 0's tokens; tkB = phase 1's packed tokens
    uint2 tkB = *(const uint2*)(htrow + base + 4);
    u32 eqA0, eqA1, eqA2, eqA3;
    {
        uint2 tkA = *(const uint2*)(htrow + base);   // pads: always in-bounds
        u32 p0 = tkA.x & 0xFFFFu, p1 = tkA.x >> 16;
        u32 p2 = tkA.y & 0xFFFFu, p3 = tkA.y >> 16;
        eqA0 = pmw[p0 * PMSTR]; eqA1 = pmw[p1 * PMSTR];
        eqA2 = pmw[p2 * PMSTR]; eqA3 = pmw[p3 * PMSTR];
    }

    int out_pkd = 0;   // 12-bit carry packet from my previous phase

#define STEP(EQ, I) do {                                                  \
        u32 cin  = ((u32)inp >> (I)) & 1u;                                \
        u32 hpin = ((u32)inp >> (8 + (I))) & 1u;                          \
        u32 hnin = ((u32)inp >> (16 + (I))) & 1u;                         \
        u32 x  = (EQ) & VP;                                               \
        u64 S  = (u64)x + VP + cin;                                       \
        u32 s2 = (u32)S;                                                  \
        u32 D0 = (s2 ^ VP) | (EQ) | VN;                                   \
        u32 HP = VN | ~(D0 | VP);                                         \
        u32 HN = VP & D0;                                                 \
        nout |= ((u32)(S >> 32) << (I)) | ((HP >> 31) << (8 + (I)))       \
                | ((HN >> 31) << (16 + (I)));                             \
        int delta = (int)((HP >> sb) & 1u) - (int)((HN >> sb) & 1u);      \
        u32 HPs = (HP << 1) | hpin;                                       \
        u32 HNs = (HN << 1) | hnin;                                       \
        VP = HNs | ~(D0 | HPs);                                           \
        VN = HPs & D0;                                                    \
        score += ((u32)(base + (I)) < hlen) ? delta : 0;                  \
    } while (0)

#pragma unroll 2
    for (int P = 0; P < NPH; ++P) {
        // token prefetch for phase P+2 (pads guarantee in-bounds, no clamps)
        uint2 tkC = *(const uint2*)(htrow + base + 8);

        // Eq loads for phase P+1 tokens (tkB, loaded last phase)
        u32 n0 = tkB.x & 0xFFFFu, n1 = tkB.x >> 16;
        u32 n2 = tkB.y & 0xFFFFu, n3 = tkB.y >> 16;
        u32 eqB0 = pmw[n0 * PMSTR], eqB1 = pmw[n1 * PMSTR];
        u32 eqB2 = pmw[n2 * PMSTR], eqB3 = pmw[n3 * PMSTR];

        // carry packet from word w-1 (its previous phase), one DPP
        int inp = row_shr1(out_pkd);
        if (isW0) inp = 0x0F00;       // cin=0, hpin=1 (D[0][j]=j), hnin=0 x4

        u32 nout = 0;
        STEP(eqA0, 0);
        STEP(eqA1, 1);
        STEP(eqA2, 2);
        STEP(eqA3, 3);
        out_pkd = (int)nout;

        // rotate pipeline
        tkB = tkC;
        eqA0 = eqB0; eqA1 = eqB1; eqA2 = eqB2; eqA3 = eqB3;
        base += RSTEP;
    }
#undef STEP

    if (isSW) sc_sh[sl] = score;
    __syncthreads();

    // ---- half-batch f64 partials: se = sum exp(x), see = sum er*e, ser = sum er
    //      (exp without max-subtraction: f64, |x| < ~6 -> exact-safe)
    if (tid < 64) {
        const bool act = tid < SPB;
        double e = 0.0, see = 0.0, ser = 0.0;
        if (act) {
            double er = (double)sc_sh[tid] / (double)m;
            double xx = (double)lp[b * SAMPLES + half * SPB + tid];
            e   = exp(xx);
            see = er * e;
            ser = er;
        }
#pragma unroll
        for (int off = 32; off > 0; off >>= 1) {
            e   += __shfl_xor(e,   off);
            see += __shfl_xor(see, off);
            ser += __shfl_xor(ser, off);
        }
        if (tid == 0) {
            double* p = part + (size_t)blk * 3;
            p[0] = e; p[1] = see; p[2] = ser;
        }
    }
}

// 1 block, 128 threads: thread b combines the two half-batch partials,
// then 2-wave reduce -> scalar.
//   loss_b = (see0+see1)/(se0+se1) - (ser0+ser1)/64;  out = mean over b,s
__global__ __launch_bounds__(128) void mer_final(const double* __restrict__ part,
                                                 float* __restrict__ out)
{
    const int b = threadIdx.x;        // 0..127
    const double* p0 = part + (size_t)(2 * b)     * 3;
    const double* p1 = part + (size_t)(2 * b + 1) * 3;
    double se  = p0[0] + p1[0];
    double see = p0[1] + p1[1];
    double ser = p0[2] + p1[2];
    double v = see / se - ser * (1.0 / SAMPLES);

#pragma unroll
    for (int off = 32; off > 0; off >>= 1)
        v += __shfl_xor(v, off);

    __shared__ double red[2];
    if ((b & 63) == 0) red[b >> 6] = v;
    __syncthreads();
    if (b == 0) out[0] = (float)((red[0] + red[1]) / (double)(BATCH * SAMPLES));
}

extern "C" void kernel_launch(void* const* d_in, const int* in_sizes, int n_in,
                              void* d_out, int out_size, void* d_ws, size_t ws_size,
                              hipStream_t stream)
{
    const float* lp  = (const float*)d_in[0];
    const int*   ref = (const int*)d_in[1];
    const int*   hyp = (const int*)d_in[2];

    double* part = (double*)d_ws;     // 256 blocks x 3 f64
    float*  out  = (float*)d_out;

    mer_edit<<<2 * BATCH, 256, 0, stream>>>(lp, ref, hyp, part);
    mer_final<<<1, 128, 0, stream>>>(part, out);
}

// Round 14
// 87.113 us; speedup vs baseline: 1.1923x; 1.0032x over previous
//
#include <hip/hip_runtime.h>
#include <stdint.h>

// MinimumErrorRateLoss: unit-cost Levenshtein via Myers/Hyyrö bit-parallel DP.
// R14 = R13 (87.4 µs) with a DEEPER SOFTWARE PIPELINE in the phase loop:
//   Eq gathers prefetched 2 phases ahead (was 1), tokens 4 phases ahead
//   (was 2). Theory: at 1 wave/SIMD the per-phase ~400 cyc unexplained gap
//   is exposed LDS gather latency (random-token bank conflicts, ~120+ cyc)
//   landing inside the next phase's lgkmcnt wait. 2-phase slack (~1500 cyc)
//   guarantees loads land. Costs ~8 VGPRs + TAILPAD 40->48 (HTROW 332).
//   Hot-loop STEP math, grid, staging, epilogue identical to R13.
//
// Layout (fixed problem size):
//   log_probs: (128, 64) f32      -> lp[b*64+s]
//   ref:       (256, 128) i32     -> ref[j*128+b]   (shared across samples)
//   hyp:       (256, 128, 64) i32 -> hyp[t*8192 + b*64 + s]
//   out:       scalar f32
// EOS = 0, INCLUDE_EOS -> len = first-EOS-idx + 1, else T.

#define BATCH   128
#define SAMPLES 64
#define RLEN    256
#define HLEN    256
#define NSEQ    (BATCH*SAMPLES)
#define NTOK    1000
#define PADTOK  1000       // pm has 1001 rows; row 1000 stays all-zero
#define SPB     32         // samples per block
#define PMSTR   9          // pm row stride in u32 (8 data + 1 pad)
#define HEADPAD 28         // pad tokens before t=0 (covers base >= -28)
#define HTROW   332        // 28 + 256 + 48 u16 = 664 B/row (8-B aligned)
#define RSTEP   4          // DP steps per systolic phase
#define NPH     72         // 256/4 + 8 - 1 = 71, +1 (even, for unroll 2)

typedef unsigned long long u64;
typedef unsigned int       u32;

// DPP row_shr:1 -> lane i reads lane i-1 within rows of 16; row-lane-0 gets 0.
__device__ __forceinline__ int row_shr1(int x) {
    return __builtin_amdgcn_mov_dpp(x, 0x111, 0xf, 0xf, true);
}

__global__ __launch_bounds__(256) void mer_edit(const float* __restrict__ lp,
                                                const int* __restrict__ ref,
                                                const int* __restrict__ hyp,
                                                double* __restrict__ part)
{
    const int blk  = blockIdx.x;      // 0..255
    const int b    = blk >> 1;        // batch element
    const int half = blk & 1;         // sample half (0: s 0..31, 1: s 32..63)
    const int tid  = threadIdx.x;     // 0..255
    const int w    = tid & 7;         // u32 word 0..7
    const int sl   = tid >> 3;        // local sample 0..31

    __shared__ __align__(16) u32 pm[9012];                   // 1001*9=9009 (+pad)
    __shared__ __align__(8)  unsigned short ht[SPB * HTROW]; // 21248 B
    __shared__ int sc_sh[SPB];
    __shared__ int m_sh;

    if (tid == 0) m_sh = RLEN;

    // ---- zero PM (9012 u32 = 2253 int4) ----
    for (int i = tid; i < 2253; i += 256)
        ((int4*)pm)[i] = int4{0, 0, 0, 0};

    // ---- fill ht pad regions with PADTOK ----
    // row = 166 u32: head [0,14), data [14,142), tail [142,166) -> 38 pads
    {
        const int r = tid >> 3, c = tid & 7;       // row 0..31, chunk 0..7
        u32* rowp = (u32*)ht + r * (HTROW / 2);
#pragma unroll
        for (int j0 = 0; j0 < 5; ++j0) {
            int j = c * 5 + j0;                    // 0..39; need 0..37
            if (j < 38) {
                int off = (j < 14) ? j : (142 + (j - 14));
                rowp[off] = 0x03E803E8u;           // PADTOK | PADTOK<<16
            }
        }
    }

    // ---- stage hyp slab TRANSPOSED, pair-packed:
    //      ht[s][HEADPAD + 2p..2p+1] <- one u32 write (little-endian: lo=2p)
#pragma unroll
    for (int it = 0; it < 4; it++) {
        int idx = it * 256 + tid;     // 0..1023
        int p   = idx >> 3;           // t-pair 0..127
        int s4  = (idx & 7) * 4;      // 0,4,..,28
        const int* gp = hyp + b * SAMPLES + half * SPB + s4;
        int4 v0 = *(const int4*)(gp + (2 * p)     * NSEQ);
        int4 v1 = *(const int4*)(gp + (2 * p + 1) * NSEQ);
        u32* col = (u32*)ht + (HEADPAD / 2) + p;
        col[(s4 + 0) * (HTROW / 2)] = (u32)(unsigned short)v0.x | ((u32)(unsigned short)v1.x << 16);
        col[(s4 + 1) * (HTROW / 2)] = (u32)(unsigned short)v0.y | ((u32)(unsigned short)v1.y << 16);
        col[(s4 + 2) * (HTROW / 2)] = (u32)(unsigned short)v0.z | ((u32)(unsigned short)v1.z << 16);
        col[(s4 + 3) * (HTROW / 2)] = (u32)(unsigned short)v0.w | ((u32)(unsigned short)v1.w << 16);
    }

    // ---- ref column: one token per thread (j = tid) ----
    const int rt = ref[tid * BATCH + b];
    __syncthreads();                  // m_sh + pm zero done
    if (rt == 0) atomicMin(&m_sh, tid);
    __syncthreads();
    const int m = (m_sh < RLEN) ? (m_sh + 1) : RLEN;   // ref_len, 1..256
    if (tid < m)
        atomicOr(&pm[rt * PMSTR + (tid >> 5)], 1u << (tid & 31));
    __syncthreads();                  // pm + ht ready

    // ---- per-sample hyp_len: thread (sl,w) scans t in [32w, 32w+32) ----
    u32 hlen;
    {
        const u32* rowp32 = (const u32*)(ht + sl * HTROW + HEADPAD);
        int e = 256;
#pragma unroll
        for (int j = 0; j < 16; j++) {
            u32 v  = rowp32[w * 16 + j];
            int t0 = w * 32 + 2 * j;
            if ((v & 0xFFFFu) == 0) e = min(e, t0);
            if ((v >> 16)     == 0) e = min(e, t0 + 1);
        }
        e = min(e, __shfl_xor(e, 1));   // reduce across the 8 word-lanes
        e = min(e, __shfl_xor(e, 2));   // (contiguous: tid = sl*8 + w)
        e = min(e, __shfl_xor(e, 4));
        hlen = (e < 256) ? (u32)(e + 1) : 256u;
    }

    // ---- systolic-in-wave Myers, u32 words, 4 steps/phase ----
    const int  sw   = (m - 1) >> 5, sb = (m - 1) & 31;  // score bit location
    const bool isW0 = (w == 0);
    const bool isSW = (w == sw);
    const u32* pmw  = pm + w;
    const unsigned short* htrow = ht + sl * HTROW + HEADPAD;

    u32  VP = ~0u, VN = 0u;
    int  score = m;
    int  base  = -(w << 2);           // this phase's first DP step (mult of 4)

    // deep pipeline prime (pads make every read in-bounds):
    //   eqA: Eq for phase 0 (ready)   eqB: Eq for phase 1 (ready)
    //   tkC: tokens for phase 2       tkD: tokens for phase 3
    uint2 tkC, tkD;
    u32 eqA0, eqA1, eqA2, eqA3, eqB0, eqB1, eqB2, eqB3;
    {
        uint2 tkA = *(const uint2*)(htrow + base);
        uint2 tkB = *(const uint2*)(htrow + base + 4);
        tkC = *(const uint2*)(htrow + base + 8);
        tkD = *(const uint2*)(htrow + base + 12);
        u32 p0 = tkA.x & 0xFFFFu, p1 = tkA.x >> 16;
        u32 p2 = tkA.y & 0xFFFFu, p3 = tkA.y >> 16;
        eqA0 = pmw[p0 * PMSTR]; eqA1 = pmw[p1 * PMSTR];
        eqA2 = pmw[p2 * PMSTR]; eqA3 = pmw[p3 * PMSTR];
        u32 q0 = tkB.x & 0xFFFFu, q1 = tkB.x >> 16;
        u32 q2 = tkB.y & 0xFFFFu, q3 = tkB.y >> 16;
        eqB0 = pmw[q0 * PMSTR]; eqB1 = pmw[q1 * PMSTR];
        eqB2 = pmw[q2 * PMSTR]; eqB3 = pmw[q3 * PMSTR];
    }

    int out_pkd = 0;   // 12-bit carry packet from my previous phase

#define STEP(EQ, I) do {                                                  \
        u32 cin  = ((u32)inp >> (I)) & 1u;                                \
        u32 hpin = ((u32)inp >> (8 + (I))) & 1u;                          \
        u32 hnin = ((u32)inp >> (16 + (I))) & 1u;                         \
        u32 x  = (EQ) & VP;                                               \
        u64 S  = (u64)x + VP + cin;                                       \
        u32 s2 = (u32)S;                                                  \
        u32 D0 = (s2 ^ VP) | (EQ) | VN;                                   \
        u32 HP = VN | ~(D0 | VP);                                         \
        u32 HN = VP & D0;                                                 \
        nout |= ((u32)(S >> 32) << (I)) | ((HP >> 31) << (8 + (I)))       \
                | ((HN >> 31) << (16 + (I)));                             \
        int delta = (int)((HP >> sb) & 1u) - (int)((HN >> sb) & 1u);      \
        u32 HPs = (HP << 1) | hpin;                                       \
        u32 HNs = (HN << 1) | hnin;                                       \
        VP = HNs | ~(D0 | HPs);                                           \
        VN = HPs & D0;                                                    \
        score += ((u32)(base + (I)) < hlen) ? delta : 0;                  \
    } while (0)

#pragma unroll 2
    for (int P = 0; P < NPH; ++P) {
        // token prefetch for phase P+4 (pads guarantee in-bounds, no clamps)
        uint2 tkE = *(const uint2*)(htrow + base + 16);

        // Eq gather for phase P+2 from tkC (tokens landed 2 phases ago)
        u32 n0 = tkC.x & 0xFFFFu, n1 = tkC.x >> 16;
        u32 n2 = tkC.y & 0xFFFFu, n3 = tkC.y >> 16;
        u32 eqC0 = pmw[n0 * PMSTR], eqC1 = pmw[n1 * PMSTR];
        u32 eqC2 = pmw[n2 * PMSTR], eqC3 = pmw[n3 * PMSTR];

        // carry packet from word w-1 (its previous phase), one DPP
        int inp = row_shr1(out_pkd);
        if (isW0) inp = 0x0F00;       // cin=0, hpin=1 (D[0][j]=j), hnin=0 x4

        // STEPs consume eqA, loaded 2 phases ago (~1500 cyc slack)
        u32 nout = 0;
        STEP(eqA0, 0);
        STEP(eqA1, 1);
        STEP(eqA2, 2);
        STEP(eqA3, 3);
        out_pkd = (int)nout;

        // rotate pipeline
        eqA0 = eqB0; eqA1 = eqB1; eqA2 = eqB2; eqA3 = eqB3;
        eqB0 = eqC0; eqB1 = eqC1; eqB2 = eqC2; eqB3 = eqC3;
        tkC = tkD; tkD = tkE;
        base += RSTEP;
    }
#undef STEP

    if (isSW) sc_sh[sl] = score;
    __syncthreads();

    // ---- half-batch f64 partials: se = sum exp(x), see = sum er*e, ser = sum er
    //      (exp without max-subtraction: f64, |x| < ~6 -> exact-safe)
    if (tid < 64) {
        const bool act = tid < SPB;
        double e = 0.0, see = 0.0, ser = 0.0;
        if (act) {
            double er = (double)sc_sh[tid] / (double)m;
            double xx = (double)lp[b * SAMPLES + half * SPB + tid];
            e   = exp(xx);
            see = er * e;
            ser = er;
        }
#pragma unroll
        for (int off = 32; off > 0; off >>= 1) {
            e   += __shfl_xor(e,   off);
            see += __shfl_xor(see, off);
            ser += __shfl_xor(ser, off);
        }
        if (tid == 0) {
            double* p = part + (size_t)blk * 3;
            p[0] = e; p[1] = see; p[2] = ser;
        }
    }
}

// 1 block, 128 threads: thread b combines the two half-batch partials,
// then 2-wave reduce -> scalar.
//   loss_b = (see0+see1)/(se0+se1) - (ser0+ser1)/64;  out = mean over b,s
__global__ __launch_bounds__(128) void mer_final(const double* __restrict__ part,
                                                 float* __restrict__ out)
{
    const int b = threadIdx.x;        // 0..127
    const double* p0 = part + (size_t)(2 * b)     * 3;
    const double* p1 = part + (size_t)(2 * b + 1) * 3;
    double se  = p0[0] + p1[0];
    double see = p0[1] + p1[1];
    double ser = p0[2] + p1[2];
    double v = see / se - ser * (1.0 / SAMPLES);

#pragma unroll
    for (int off = 32; off > 0; off >>= 1)
        v += __shfl_xor(v, off);

    __shared__ double red[2];
    if ((b & 63) == 0) red[b >> 6] = v;
    __syncthreads();
    if (b == 0) out[0] = (float)((red[0] + red[1]) / (double)(BATCH * SAMPLES));
}

extern "C" void kernel_launch(void* const* d_in, const int* in_sizes, int n_in,
                              void* d_out, int out_size, void* d_ws, size_t ws_size,
                              hipStream_t stream)
{
    const float* lp  = (const float*)d_in[0];
    const int*   ref = (const int*)d_in[1];
    const int*   hyp = (const int*)d_in[2];

    double* part = (double*)d_ws;     // 256 blocks x 3 f64
    float*  out  = (float*)d_out;

    mer_edit<<<2 * BATCH, 256, 0, stream>>>(lp, ref, hyp, part);
    mer_final<<<1, 128, 0, stream>>>(part, out);
}